// Round 1
// baseline (77.883 us; speedup 1.0000x reference)
//
#include <hip/hip_runtime.h>

// Quanvolutional layer: 4-qubit statevector sim per 2x2 patch.
// x: [64,1,256,256] f32, weights: [4] f32, out: [64,4,128,128] f32.
// One thread per patch; full 16-amplitude complex state in registers.

#define PI_F 3.14159265358979323846f

__global__ __launch_bounds__(256) void quanv_kernel(
    const float* __restrict__ x,
    const float* __restrict__ w,
    float* __restrict__ out)
{
    const unsigned n   = blockIdx.x * 256u + threadIdx.x;   // patch id, < 1048576
    const unsigned b   = n >> 14;          // image (128*128 patches per image)
    const unsigned rem = n & 16383u;
    const unsigned i   = rem >> 7;         // patch row
    const unsigned j   = rem & 127u;       // patch col

    // ---- load 2x2 patch (two coalesced float2 loads) ----
    const float2* x2 = reinterpret_cast<const float2*>(x);
    const unsigned base = b * 32768u + i * 256u + j;  // float2 index: row 2i, col 2j
    const float2 r0 = x2[base];
    const float2 r1 = x2[base + 128u];
    const float p0 = r0.x, p1 = r0.y, p2 = r1.x, p3 = r1.y; // wires 0..3

    // ---- normalize to half-angles in [0, pi/2] ----
    const float mn = fminf(fminf(p0, p1), fminf(p2, p3));
    const float mx = fmaxf(fmaxf(p0, p1), fmaxf(p2, p3));
    const float inv = (0.5f * PI_F) / (mx - mn + 1e-8f);
    const float h0 = (p0 - mn) * inv;
    const float h1 = (p1 - mn) * inv;
    const float h2 = (p2 - mn) * inv;
    const float h3 = (p3 - mn) * inv;

    float cA0, sA0, cA1, sA1, cA2, sA2, cA3, sA3;
    __sincosf(h0, &sA0, &cA0);
    __sincosf(h1, &sA1, &cA1);
    __sincosf(h2, &sA2, &cA2);
    __sincosf(h3, &sA3, &cA3);

    // ---- gate params (uniform; broadcast loads hit L2) ----
    float cw[4], sw[4];
    #pragma unroll
    for (int k = 0; k < 4; ++k) {
        const float h = 0.5f * w[k];
        sw[k] = __sinf(h);
        cw[k] = __cosf(h);
    }

    // ---- initial product state (real) ----
    // index = a*8 + b*4 + c*2 + d  (wire0 = bit3 ... wire3 = bit0)
    float re[16], im[16];
    float e01[4], e23[4];
    e01[0] = cA0 * cA1; e01[1] = cA0 * sA1; e01[2] = sA0 * cA1; e01[3] = sA0 * sA1;
    e23[0] = cA2 * cA3; e23[1] = cA2 * sA3; e23[2] = sA2 * cA3; e23[3] = sA2 * sA3;
    #pragma unroll
    for (int u = 0; u < 4; ++u)
        #pragma unroll
        for (int v = 0; v < 4; ++v) {
            re[u * 4 + v] = e01[u] * e23[v];
            im[u * 4 + v] = 0.0f;
        }

    // ---- RX(w0) on wire 0 (bit 8): U = [[c, -is],[-is, c]] ----
    {
        const float c = cw[0], s = sw[0];
        #pragma unroll
        for (int k = 0; k < 8; ++k) {
            const float r0v = re[k],     i0v = im[k];
            const float r1v = re[k + 8], i1v = im[k + 8];
            re[k]     = c * r0v + s * i1v;
            im[k]     = c * i0v - s * r1v;
            re[k + 8] = c * r1v + s * i0v;
            im[k + 8] = c * i1v - s * r0v;
        }
    }

    // ---- RX(w1) on wire 1 (bit 4) ----
    {
        const float c = cw[1], s = sw[1];
        #pragma unroll
        for (int k = 0; k < 16; ++k) {
            if (k & 4) continue;  // compile-time predicate
            const float r0v = re[k],     i0v = im[k];
            const float r1v = re[k + 4], i1v = im[k + 4];
            re[k]     = c * r0v + s * i1v;
            im[k]     = c * i0v - s * r1v;
            re[k + 4] = c * r1v + s * i0v;
            im[k + 4] = c * i1v - s * r0v;
        }
    }

    // ---- CNOTs: compile-time register swaps ----
    // CNOT(ctrl=3, tgt=2): bit0==1 -> swap k <-> k^2
    #pragma unroll
    for (int k = 0; k < 16; ++k) {
        if ((k & 1) && !(k & 2)) {
            float t;
            t = re[k]; re[k] = re[k ^ 2]; re[k ^ 2] = t;
            t = im[k]; im[k] = im[k ^ 2]; im[k ^ 2] = t;
        }
    }
    // CNOT(ctrl=2, tgt=0): bit1==1 -> swap k <-> k^8
    #pragma unroll
    for (int k = 0; k < 8; ++k) {
        if (k & 2) {
            float t;
            t = re[k]; re[k] = re[k ^ 8]; re[k ^ 8] = t;
            t = im[k]; im[k] = im[k ^ 8]; im[k ^ 8] = t;
        }
    }
    // CNOT(ctrl=3, tgt=0): bit0==1 -> swap k <-> k^8
    #pragma unroll
    for (int k = 0; k < 8; ++k) {
        if (k & 1) {
            float t;
            t = re[k]; re[k] = re[k ^ 8]; re[k ^ 8] = t;
            t = im[k]; im[k] = im[k ^ 8]; im[k ^ 8] = t;
        }
    }

    // ---- RY(w2) on wire 0 (bit 8): [[c,-s],[s,c]] (real) ----
    {
        const float c = cw[2], s = sw[2];
        #pragma unroll
        for (int k = 0; k < 8; ++k) {
            float a, bb;
            a = re[k]; bb = re[k + 8];
            re[k] = c * a - s * bb; re[k + 8] = s * a + c * bb;
            a = im[k]; bb = im[k + 8];
            im[k] = c * a - s * bb; im[k + 8] = s * a + c * bb;
        }
    }

    // ---- RY(w3) on wire 3 (bit 1) ----
    {
        const float c = cw[3], s = sw[3];
        #pragma unroll
        for (int k = 0; k < 16; k += 2) {
            float a, bb;
            a = re[k]; bb = re[k + 1];
            re[k] = c * a - s * bb; re[k + 1] = s * a + c * bb;
            a = im[k]; bb = im[k + 1];
            im[k] = c * a - s * bb; im[k + 1] = s * a + c * bb;
        }
    }

    // ---- probabilities and <Z_k> ----
    float z0 = 0.f, z1 = 0.f, z2 = 0.f, z3 = 0.f;
    #pragma unroll
    for (int k = 0; k < 16; ++k) {
        const float p = re[k] * re[k] + im[k] * im[k];
        z0 += (k & 8) ? -p : p;
        z1 += (k & 4) ? -p : p;
        z2 += (k & 2) ? -p : p;
        z3 += (k & 1) ? -p : p;
    }

    // ---- store: out[b][k][i][j], planes 128x128 ----
    const unsigned ob = b * 65536u + i * 128u + j;
    out[ob]           = z0;
    out[ob + 16384u]  = z1;
    out[ob + 32768u]  = z2;
    out[ob + 49152u]  = z3;
}

extern "C" void kernel_launch(void* const* d_in, const int* in_sizes, int n_in,
                              void* d_out, int out_size, void* d_ws, size_t ws_size,
                              hipStream_t stream) {
    const float* x = (const float*)d_in[0];   // [64,1,256,256]
    const float* w = (const float*)d_in[1];   // [4]
    float* out = (float*)d_out;               // [64,4,128,128]

    const int n_patches = in_sizes[0] / 4;    // 1,048,576
    const int blocks = (n_patches + 255) / 256;
    quanv_kernel<<<dim3(blocks), dim3(256), 0, stream>>>(x, w, out);
}

// Round 2
// 68.241 us; speedup vs baseline: 1.1413x; 1.1413x over previous
//
#include <hip/hip_runtime.h>

// Quanvolutional layer, closed-form (Heisenberg picture).
// x: [64,1,256,256] f32, weights: [4] f32, out: [64,4,128,128] f32.
//
// Per 2x2 patch with normalized angles a0..a3 in [0, pi]:
//   z0 = cos(w0)cos(w2)*cos(a0)cos(a2) - sin(w2)*sin(a0)
//   z1 = cos(w1)*cos(a1)
//   z2 = cos(a2)*cos(a3)
//   z3 = cos(w3)*cos(a3) - sin(w3)*sin(a0)sin(a2)sin(a3)
// Derived by pulling Z_k back through RY3,RY0,CNOT(3,0),CNOT(2,0),CNOT(3,2),
// RX1,RX0 and using <Y>=0, <Z>=cos a, <X>=sin a on the real product state.
//
// 2 horizontally-adjacent patches per thread -> float4 loads, float2 stores.

#define PI_F 3.14159265358979323846f

__global__ __launch_bounds__(256) void quanv_kernel(
    const float* __restrict__ x,
    const float* __restrict__ w,
    float* __restrict__ out)
{
    const unsigned t   = blockIdx.x * 256u + threadIdx.x;   // < 524288
    const unsigned b   = t >> 13;          // image (128 rows * 64 jj per image)
    const unsigned rem = t & 8191u;
    const unsigned i   = rem >> 6;         // patch row 0..127
    const unsigned jj  = rem & 63u;        // patch-pair col 0..63 (covers cols 4jj..4jj+3)

    // ---- uniform weight trig (cheap: 6 quarter-rate trans ops) ----
    const float cw0 = __cosf(w[0]);
    const float cw1 = __cosf(w[1]);
    float sw2, cw2, sw3, cw3;
    __sincosf(w[2], &sw2, &cw2);
    __sincosf(w[3], &sw3, &cw3);
    const float c02 = cw0 * cw2;

    // ---- load two 2x2 patches (float4 per row, 16B/lane coalesced) ----
    const float4* x4 = reinterpret_cast<const float4*>(x);
    const unsigned base = b * 16384u + (2u * i) * 64u + jj;
    const float4 r0 = x4[base];
    const float4 r1 = x4[base + 64u];

    float zA[4], zB[4];

    #pragma unroll
    for (int p = 0; p < 2; ++p) {
        const float p0 = p ? r0.z : r0.x;
        const float p1 = p ? r0.w : r0.y;
        const float p2 = p ? r1.z : r1.x;
        const float p3 = p ? r1.w : r1.y;

        const float mn  = fminf(fminf(p0, p1), fminf(p2, p3));
        const float mx  = fmaxf(fmaxf(p0, p1), fmaxf(p2, p3));
        const float inv = PI_F * __frcp_rn(mx - mn + 1e-8f);

        const float a0 = (p0 - mn) * inv;
        const float a1 = (p1 - mn) * inv;
        const float a2 = (p2 - mn) * inv;
        const float a3 = (p3 - mn) * inv;

        float sa0, ca0, sa2, ca2, sa3, ca3;
        __sincosf(a0, &sa0, &ca0);
        __sincosf(a2, &sa2, &ca2);
        __sincosf(a3, &sa3, &ca3);
        const float ca1 = __cosf(a1);

        float* z = p ? zB : zA;
        z[0] = c02 * ca0 * ca2 - sw2 * sa0;
        z[1] = cw1 * ca1;
        z[2] = ca2 * ca3;
        z[3] = cw3 * ca3 - sw3 * sa0 * sa2 * sa3;
    }

    // ---- store: out[b][k][i][2jj..2jj+1] as float2 ----
    float2* out2 = reinterpret_cast<float2*>(out);
    const unsigned ob = b * 32768u + i * 64u + jj;   // float2 index in plane 0
    #pragma unroll
    for (int k = 0; k < 4; ++k)
        out2[ob + (unsigned)k * 8192u] = make_float2(zA[k], zB[k]);
}

extern "C" void kernel_launch(void* const* d_in, const int* in_sizes, int n_in,
                              void* d_out, int out_size, void* d_ws, size_t ws_size,
                              hipStream_t stream) {
    const float* x = (const float*)d_in[0];   // [64,1,256,256]
    const float* w = (const float*)d_in[1];   // [4]
    float* out = (float*)d_out;               // [64,4,128,128]

    // 524288 threads: 2 patches each
    quanv_kernel<<<dim3(2048), dim3(256), 0, stream>>>(x, w, out);
}